// Round 6
// baseline (6672.832 us; speedup 1.0000x reference)
//
#include <hip/hip_runtime.h>
#include <cmath>

#define TSTEPS 256
#define DIM 1024

typedef _Float16 half8v __attribute__((ext_vector_type(8)));
typedef _Float16 half4v __attribute__((ext_vector_type(4)));
typedef float f32x4 __attribute__((ext_vector_type(4)));
typedef unsigned long long u64;

// ws layout:
//   xh  : [T][B][D] fp16 x (t-major), 16,777,216 halfs
//   h0r : [4 slot][mb:2][nb:64][b:32][d:16] blocked ring for h0
//   h1r : same, for h1
//   cnts: leaf0[p][16 leaves, 16-word stride], leaf1[...] (131,072 uints)
// Phase p: cell0 computes h0[t=p] (reads x[p], h0[p-1]); cell1 computes
// h1[t=p-1] (reads h0[p-1], h1[p-2]). h[t] in ring slot t&3.
//
// R9:  h broadcast via L2 (agent stores; acquire-inv; cached loads).
// R10: acquire-fence; signal right after vmcnt(0).
// R11: burn-spin -> NULL (waits ~20% of wall).
// R12: gates XOR-swizzle + blocked h-ring + fast tanh (-33%).
// R13: 32x64 tile: per-CU ingest halved to 128KB/phase (-13%); gates LDS
//      round trip (~1030cy) + conflicts (~630cy) now ~30% of 5370cy phase.
// R14 (this round):
//   1) gates: ds_add_f32 accumulation into [c:64][m:32] (8KB), zeroed at
//      phase start (overlaps poll). LDS bytes 128KB->64KB/phase; pointwise
//      reduce 32 reads -> 4. Address map m -> (m&~3)|((m+(m>>2))&3) ^ key
//      rotates bank bits 0-1 by q so half-wave adds are <=2-way (free);
//      key = (c&7)<<2 as before. Static acc[nt][r] indexing.
//   2) h-store: direct per-thread 2B agent stores (ring is [b][d] blocked ->
//      base+tid contiguous, 1KB/block); hlds gather deleted.
//   3) poll pacing s_sleep(4) -> s_sleep(1).

__global__ void prologue(const float* __restrict__ x, _Float16* __restrict__ xh,
                         _Float16* __restrict__ hrings, unsigned* __restrict__ cnts)
{
    size_t gid  = (size_t)blockIdx.x * blockDim.x + threadIdx.x;
    size_t nthr = (size_t)gridDim.x * blockDim.x;
    for (size_t i = gid; i < 4194304u; i += nthr) {     // x[b][t][d4] -> xh[t][b][d]
        float4 v = ((const float4*)x)[i];
        half4v h = {(_Float16)v.x, (_Float16)v.y, (_Float16)v.z, (_Float16)v.w};
        unsigned d4 = (unsigned)i & 255u, t = ((unsigned)i >> 8) & 255u, b = (unsigned)i >> 16;
        ((half4v*)(xh + ((size_t)t * 64 + b) * 1024))[d4] = h;
    }
    for (size_t i = gid; i < 65536u; i += nthr) {       // zero both h rings
        half8v z = {};
        ((half8v*)hrings)[i] = z;
    }
    for (size_t i = gid; i < 139264u; i += nthr) cnts[i] = 0u;
}

// 256 blocks x 512 threads (8 waves), 1 block/CU. Blocks 0..127: cell0;
// 128..255: cell1. Block (cell, mb=wb>>6, nb=wb&63) owns batch rows
// mb*32..+32, h-dims nb*16..+16. Wave kq owns K-slice [kq*256,+256)
// (cell0: k<1024 = x, k>=1024 = h0; cell1: h0 then h1). Weights in
// registers (32 x half8v). A held as A[2][8]. Signal: 16 leaf counters/
// cell/phase. Wait: wave 0 lanes 0..31 poll leaves of BOTH dep sets +
// ballot, s_sleep(1) pacing.
__global__ __launch_bounds__(512, 2)
void lstm_persistent(const float* __restrict__ Wx0, const float* __restrict__ Wh0,
                     const float* __restrict__ b0,
                     const float* __restrict__ Wx1, const float* __restrict__ Wh1,
                     const float* __restrict__ b1,
                     const _Float16* __restrict__ xh, _Float16* __restrict__ h0r,
                     _Float16* __restrict__ h1r, unsigned* __restrict__ cnts,
                     float* __restrict__ out)
{
    extern __shared__ char smem[];
    _Float16* wfrag = (_Float16*)smem;           // 128 KB per staging pass
    float*    gates = (float*)smem;              // [c:64][m:32] fp32, 8 KB (aliases)

    const int tid  = threadIdx.x;
    const int blk  = blockIdx.x;
    const int cell = blk >> 7;
    const int wb   = blk & 127;
    const int mb   = wb >> 6, nb = wb & 63;
    const int lane = tid & 63, kq = tid >> 6;
    const int n15 = lane & 15, q = lane >> 4;

    unsigned* leaf0 = cnts;                      // [(p*16+leaf)*16]
    unsigned* leaf1 = cnts + 65536;
    unsigned* leafm = cell ? leaf1 : leaf0;

    // ---- one-time: weights -> regs via two 128KB LDS passes ----
    half8v wreg[32];                             // [nt*8 + kt], nt 0..3
    {
        const float* passW[2] = { cell ? Wx1 : Wx0, cell ? Wh1 : Wh0 };
        for (int ps = 0; ps < 2; ++ps) {
            const float* W = passW[ps];
            for (int idx = tid; idx < 16384; idx += 512) {
                int k = idx >> 4;                // 0..1023
                int cc0 = (idx & 15) * 4;        // block-col 0..60
                const float* src = W + (size_t)k * 4096
                                   + (cc0 >> 4) * 1024 + nb * 16 + (cc0 & 15);
                float4 v = *(const float4*)src;
                int skq = k >> 8, kt = (k >> 5) & 7, qp = (k >> 3) & 3, j = k & 7;
                float vv[4] = {v.x, v.y, v.z, v.w};
                #pragma unroll
                for (int e = 0; e < 4; ++e) {
                    int cc = cc0 + e, nt = cc >> 4, nn = cc & 15;
                    wfrag[((((skq * 4 + nt) * 8 + kt) * 64) + qp * 16 + nn) * 8 + j]
                        = (_Float16)vv[e];
                }
            }
            __syncthreads();
            if ((kq >> 2) == ps) {
                int skq = kq & 3;
                #pragma unroll
                for (int nt = 0; nt < 4; ++nt)
                    #pragma unroll
                    for (int kt = 0; kt < 8; ++kt)
                        wreg[nt * 8 + kt] = *(const half8v*)
                            &wfrag[((((skq * 4 + nt) * 8 + kt) * 64) + lane) * 8];
            }
            __syncthreads();                     // wfrag reusable / gates alias
        }
    }

    const int pm = tid >> 4, pdn = tid & 15;     // pointwise coords (m, d)
    const float* bias = cell ? b1 : b0;
    const int dimg = nb * 16 + pdn;
    const float bi = bias[0 * 1024 + dimg], bfg = bias[1 * 1024 + dimg],
                bg = bias[2 * 1024 + dimg], bo  = bias[3 * 1024 + dimg];
    float creg = 0.0f;

    // pointwise gate read address: m-row after rotation map, fixed per thread
    const int rkey  = (pdn & 7) << 2;
    const int mrow  = ((pm & ~3) | (((pm & 3) + ((pm >> 2) & 3)) & 3)) ^ rkey;

    const bool havex = (cell == 0) && (kq < 4);  // x-wave: plain cached loads

    for (int p = 0; p <= TSTEPS; ++p) {
        if (cell == 0 && p == TSTEPS) break;
        const bool active = cell ? (p >= 1) : true;

        half8v A[2][8];
        // x burst BEFORE the poll (no coherence needed; overlaps the wait)
        if (havex) {
            const _Float16* a = xh + (size_t)p * 65536
                                + (size_t)(mb * 32 + n15) * 1024 + kq * 256 + q * 8;
            #pragma unroll
            for (int mt = 0; mt < 2; ++mt)
                #pragma unroll
                for (int kt = 0; kt < 8; ++kt)
                    A[mt][kt] = *(const half8v*)(a + mt * 16384 + kt * 32);
        }

        // zero gate accumulators (overlaps wave0's poll; prev-phase reads are
        // fenced by the p-1 store barrier)
        ((f32x4*)gates)[tid] = (f32x4){0.f, 0.f, 0.f, 0.f};

        // ---- wait for dependencies: wave 0, leaf-parallel + ballot ----
        if (tid < 64) {
            if (p >= 1) {
                // set A: leaf0[p-1] (lanes 0..15). set B (lanes 16..31):
                //   cell0: leaf1[p-3] (ring WAR), cell1: leaf1[p-1]
                const unsigned* addr = nullptr;
                if (tid < 16) {
                    addr = leaf0 + ((p - 1) * 16 + tid) * 16;
                } else if (tid < 32) {
                    int lf = tid - 16;
                    if (cell == 0) { if (p >= 3) addr = leaf1 + ((p - 3) * 16 + lf) * 16; }
                    else           { if (p >= 2) addr = leaf1 + ((p - 1) * 16 + lf) * 16; }
                }
                bool ok = (addr == nullptr);
                while (true) {
                    if (!ok)
                        ok = __hip_atomic_load(addr, __ATOMIC_RELAXED,
                                               __HIP_MEMORY_SCOPE_AGENT) >= 8u;
                    if (__ballot(ok) == ~0ull) break;
                    __builtin_amdgcn_s_sleep(1);
                }
            }
            // ACQUIRE fence: buffer_inv -> drop possibly stale L1/L2 h lines;
            // plain cached loads below refetch from L3.
            __builtin_amdgcn_fence(__ATOMIC_ACQUIRE, "agent");
        }
        __syncthreads();

        // ---- h burst: plain cached loads from blocked ring ----
        if (active && !havex) {
            const _Float16* hb; int ks;
            if (cell == 0)   { hb = h0r + (size_t)((p - 1) & 3) * 65536; ks = kq - 4; }
            else if (kq < 4) { hb = h0r + (size_t)((p - 1) & 3) * 65536; ks = kq; }
            else             { hb = h1r + (size_t)((p - 2) & 3) * 65536; ks = kq - 4; }
            // elem (b, k): ring[mb][k>>4][b][k&15]; lane k = ks*256+kt*32+q*8+j
            const _Float16* a = hb + (size_t)mb * 32768
                                + (size_t)(ks * 16 + (q >> 1)) * 512
                                + (size_t)n15 * 16 + (q & 1) * 8;
            #pragma unroll
            for (int mt = 0; mt < 2; ++mt)
                #pragma unroll
                for (int kt = 0; kt < 8; ++kt)
                    A[mt][kt] = *(const half8v*)(a + kt * 1024 + mt * 256);
        }

        // ---- MFMA; gate partials accumulate via ds_add_f32 ----
        if (active) {
            #pragma unroll
            for (int mt = 0; mt < 2; ++mt) {
                f32x4 acc[4] = {{0.f,0.f,0.f,0.f}, {0.f,0.f,0.f,0.f},
                                {0.f,0.f,0.f,0.f}, {0.f,0.f,0.f,0.f}};
                #pragma unroll
                for (int kt = 0; kt < 8; ++kt)
                    #pragma unroll
                    for (int nt = 0; nt < 4; ++nt)
                        acc[nt] = __builtin_amdgcn_mfma_f32_16x16x32_f16(
                                      A[mt][kt], wreg[nt * 8 + kt], acc[nt], 0, 0, 0);
                const int row0 = mt * 16 + q * 4;       // row0&3 == 0
                const int key  = (n15 & 7) << 2;
                #pragma unroll
                for (int nt = 0; nt < 4; ++nt) {
                    float* gb = gates + (nt * 16 + n15) * 32;
                    #pragma unroll
                    for (int r = 0; r < 4; ++r) {
                        const int m = (row0 | ((r + q) & 3)) ^ key;
                        unsafeAtomicAdd(gb + m, acc[nt][(r + q) & 3] * 0.f
                                                + acc[nt][r]);   // keep r static
                    }
                }
            }
        }
        __syncthreads();

        // ---- pointwise: 4 gate reads, fast tanh, direct coalesced h store ----
        if (active) {
            // written location for m: (m&~3)|((m+(m>>2))&3) ^ key — mrow precomp
            float g0 = gates[(0 * 16 + pdn) * 32 + mrow] + bi;
            float g1 = gates[(1 * 16 + pdn) * 32 + mrow] + bfg;
            float g2 = gates[(2 * 16 + pdn) * 32 + mrow] + bg;
            float g3 = gates[(3 * 16 + pdn) * 32 + mrow] + bo;
            float si = 1.f / (1.f + __expf(-g0));
            float sf = 1.f / (1.f + __expf(-g1));
            float so = 1.f / (1.f + __expf(-g3));
            float tg = 1.f - 2.f / (__expf(2.f * g2) + 1.f);
            float cn = sf * creg + si * tg;
            float tc = 1.f - 2.f / (__expf(2.f * cn) + 1.f);
            float hn = so * tc;
            creg = cn;
            if (p < TSTEPS) {
                union { _Float16 h; unsigned short u; } cv; cv.h = (_Float16)hn;
                _Float16* dst = (cell ? h1r + (size_t)((p - 1) & 3) * 65536
                                      : h0r + (size_t)(p & 3) * 65536)
                                + (size_t)mb * 32768 + (size_t)nb * 512;
                __hip_atomic_store((unsigned short*)dst + tid, cv.u,
                                   __ATOMIC_RELAXED, __HIP_MEMORY_SCOPE_AGENT);
            }
            if (cell && p == TSTEPS) out[(mb * 32 + pm) * 1024 + nb * 16 + pdn] = hn;
        }

        // ---- drain own stores, barrier, signal ----
        if (p < TSTEPS) {
            if (active) {
                asm volatile("s_waitcnt vmcnt(0)" ::: "memory");   // h at L3
                __syncthreads();
            }
            if (tid == 0)
                __hip_atomic_fetch_add(leafm + (p * 16 + (wb >> 3)) * 16, 1u,
                                       __ATOMIC_RELAXED, __HIP_MEMORY_SCOPE_AGENT);
        }
    }
}

extern "C" void kernel_launch(void* const* d_in, const int* in_sizes, int n_in,
                              void* d_out, int out_size, void* d_ws, size_t ws_size,
                              hipStream_t stream)
{
    const float* x   = (const float*)d_in[0];
    const float* Wx0 = (const float*)d_in[1];
    const float* Wh0 = (const float*)d_in[2];
    const float* b0  = (const float*)d_in[3];
    const float* Wx1 = (const float*)d_in[4];
    const float* Wh1 = (const float*)d_in[5];
    const float* b1  = (const float*)d_in[6];
    float* out = (float*)d_out;

    _Float16* xh   = (_Float16*)d_ws;
    _Float16* h0r  = xh + (size_t)16777216;
    _Float16* h1r  = h0r + 262144;
    unsigned* cnts = (unsigned*)(h1r + 262144);

    hipLaunchKernelGGL(prologue, dim3(2048), dim3(256), 0, stream, x, xh, h0r, cnts);

    size_t smem = 131072;
    (void)hipFuncSetAttribute((const void*)lstm_persistent,
                              hipFuncAttributeMaxDynamicSharedMemorySize, (int)smem);

    void* args[] = {(void*)&Wx0, (void*)&Wh0, (void*)&b0,
                    (void*)&Wx1, (void*)&Wh1, (void*)&b1,
                    (void*)&xh, (void*)&h0r, (void*)&h1r,
                    (void*)&cnts, (void*)&out};
    (void)hipLaunchCooperativeKernel((const void*)lstm_persistent, dim3(256), dim3(512),
                                     args, (unsigned)smem, stream);
}

// Round 7
// 1852.457 us; speedup vs baseline: 3.6022x; 3.6022x over previous
//
#include <hip/hip_runtime.h>
#include <cmath>

#define TSTEPS 256
#define DIM 1024

typedef _Float16 half8v __attribute__((ext_vector_type(8)));
typedef _Float16 half4v __attribute__((ext_vector_type(4)));
typedef float f32x4 __attribute__((ext_vector_type(4)));
typedef unsigned long long u64;

// ws layout:
//   xh  : [T][B][D] fp16 x (t-major), 16,777,216 halfs
//   h0r : [4 slot][mb:2][nb:64][b:32][d:16] blocked ring for h0
//   h1r : same, for h1
//   cnts: leaf0[p][16 leaves, 16-word stride], leaf1[...] (131,072 uints)
// Phase p: cell0 computes h0[t=p] (reads x[p], h0[p-1]); cell1 computes
// h1[t=p-1] (reads h0[p-1], h1[p-2]). h[t] in ring slot t&3.
//
// R9:  h broadcast via L2 (agent stores; acquire-inv; cached loads).
// R10: acquire-fence; signal right after vmcnt(0).
// R11: burn-spin -> NULL (waits ~20% of wall).
// R12: gates XOR-swizzle + blocked h-ring + fast tanh (-33%).
// R13: 32x64 tile, per-CU ingest halved (-13%). Gates [c:64][kq:8][m:32],
//      b128 writes + b32 reads; the 4.1e7 conflict count is 2-way read
//      aliasing = cosmetic (free per m136).
// R14: ds_add_f32 gate accumulation -> CATASTROPHE (+234%): LDS RMW atomics
//      serialize under 8-wave contention. REVERTED. Kept the two proven-good
//      pieces: direct per-thread 2B h-store (WRITE 133->69MB, no hlds gather,
//      drain spread over all waves) and s_sleep(1) pacing.
// R15 (this round): R13 gates scheme + R14's direct store + s_sleep(1).

__global__ void prologue(const float* __restrict__ x, _Float16* __restrict__ xh,
                         _Float16* __restrict__ hrings, unsigned* __restrict__ cnts)
{
    size_t gid  = (size_t)blockIdx.x * blockDim.x + threadIdx.x;
    size_t nthr = (size_t)gridDim.x * blockDim.x;
    for (size_t i = gid; i < 4194304u; i += nthr) {     // x[b][t][d4] -> xh[t][b][d]
        float4 v = ((const float4*)x)[i];
        half4v h = {(_Float16)v.x, (_Float16)v.y, (_Float16)v.z, (_Float16)v.w};
        unsigned d4 = (unsigned)i & 255u, t = ((unsigned)i >> 8) & 255u, b = (unsigned)i >> 16;
        ((half4v*)(xh + ((size_t)t * 64 + b) * 1024))[d4] = h;
    }
    for (size_t i = gid; i < 65536u; i += nthr) {       // zero both h rings
        half8v z = {};
        ((half8v*)hrings)[i] = z;
    }
    for (size_t i = gid; i < 139264u; i += nthr) cnts[i] = 0u;
}

// 256 blocks x 512 threads (8 waves), 1 block/CU. Blocks 0..127: cell0;
// 128..255: cell1. Block (cell, mb=wb>>6, nb=wb&63) owns batch rows
// mb*32..+32, h-dims nb*16..+16. Wave kq owns K-slice [kq*256,+256)
// (cell0: k<1024 = x, k>=1024 = h0; cell1: h0 then h1). Weights in
// registers (32 x half8v). A held as A[2][8]. Signal: 16 leaf counters/
// cell/phase. Wait: wave 0 lanes 0..31 poll leaves of BOTH dep sets +
// ballot, s_sleep(1) pacing.
__global__ __launch_bounds__(512, 2)
void lstm_persistent(const float* __restrict__ Wx0, const float* __restrict__ Wh0,
                     const float* __restrict__ b0,
                     const float* __restrict__ Wx1, const float* __restrict__ Wh1,
                     const float* __restrict__ b1,
                     const _Float16* __restrict__ xh, _Float16* __restrict__ h0r,
                     _Float16* __restrict__ h1r, unsigned* __restrict__ cnts,
                     float* __restrict__ out)
{
    extern __shared__ char smem[];
    _Float16* wfrag = (_Float16*)smem;           // 128 KB per staging pass
    float*    gates = (float*)smem;              // [c:64][kq:8][m:32] fp32, 64 KB

    const int tid  = threadIdx.x;
    const int blk  = blockIdx.x;
    const int cell = blk >> 7;
    const int wb   = blk & 127;
    const int mb   = wb >> 6, nb = wb & 63;
    const int lane = tid & 63, kq = tid >> 6;
    const int n15 = lane & 15, q = lane >> 4;

    unsigned* leaf0 = cnts;                      // [(p*16+leaf)*16]
    unsigned* leaf1 = cnts + 65536;
    unsigned* leafm = cell ? leaf1 : leaf0;

    // ---- one-time: weights -> regs via two 128KB LDS passes ----
    half8v wreg[32];                             // [nt*8 + kt], nt 0..3
    {
        const float* passW[2] = { cell ? Wx1 : Wx0, cell ? Wh1 : Wh0 };
        for (int ps = 0; ps < 2; ++ps) {
            const float* W = passW[ps];
            for (int idx = tid; idx < 16384; idx += 512) {
                int k = idx >> 4;                // 0..1023
                int cc0 = (idx & 15) * 4;        // block-col 0..60
                const float* src = W + (size_t)k * 4096
                                   + (cc0 >> 4) * 1024 + nb * 16 + (cc0 & 15);
                float4 v = *(const float4*)src;
                int skq = k >> 8, kt = (k >> 5) & 7, qp = (k >> 3) & 3, j = k & 7;
                float vv[4] = {v.x, v.y, v.z, v.w};
                #pragma unroll
                for (int e = 0; e < 4; ++e) {
                    int cc = cc0 + e, nt = cc >> 4, nn = cc & 15;
                    wfrag[((((skq * 4 + nt) * 8 + kt) * 64) + qp * 16 + nn) * 8 + j]
                        = (_Float16)vv[e];
                }
            }
            __syncthreads();
            if ((kq >> 2) == ps) {
                int skq = kq & 3;
                #pragma unroll
                for (int nt = 0; nt < 4; ++nt)
                    #pragma unroll
                    for (int kt = 0; kt < 8; ++kt)
                        wreg[nt * 8 + kt] = *(const half8v*)
                            &wfrag[((((skq * 4 + nt) * 8 + kt) * 64) + lane) * 8];
            }
            __syncthreads();                     // wfrag reusable / gates alias
        }
    }

    const int pm = tid >> 4, pdn = tid & 15;     // pointwise coords (m, d)
    const float* bias = cell ? b1 : b0;
    const int dimg = nb * 16 + pdn;
    const float bi = bias[0 * 1024 + dimg], bfg = bias[1 * 1024 + dimg],
                bg = bias[2 * 1024 + dimg], bo  = bias[3 * 1024 + dimg];
    float creg = 0.0f;

    const bool havex = (cell == 0) && (kq < 4);  // x-wave: plain cached loads

    for (int p = 0; p <= TSTEPS; ++p) {
        if (cell == 0 && p == TSTEPS) break;
        const bool active = cell ? (p >= 1) : true;

        half8v A[2][8];
        // x burst BEFORE the poll (no coherence needed; overlaps the wait)
        if (havex) {
            const _Float16* a = xh + (size_t)p * 65536
                                + (size_t)(mb * 32 + n15) * 1024 + kq * 256 + q * 8;
            #pragma unroll
            for (int mt = 0; mt < 2; ++mt)
                #pragma unroll
                for (int kt = 0; kt < 8; ++kt)
                    A[mt][kt] = *(const half8v*)(a + mt * 16384 + kt * 32);
        }

        // ---- wait for dependencies: wave 0, leaf-parallel + ballot ----
        if (tid < 64) {
            if (p >= 1) {
                // set A: leaf0[p-1] (lanes 0..15). set B (lanes 16..31):
                //   cell0: leaf1[p-3] (ring WAR), cell1: leaf1[p-1]
                const unsigned* addr = nullptr;
                if (tid < 16) {
                    addr = leaf0 + ((p - 1) * 16 + tid) * 16;
                } else if (tid < 32) {
                    int lf = tid - 16;
                    if (cell == 0) { if (p >= 3) addr = leaf1 + ((p - 3) * 16 + lf) * 16; }
                    else           { if (p >= 2) addr = leaf1 + ((p - 1) * 16 + lf) * 16; }
                }
                bool ok = (addr == nullptr);
                while (true) {
                    if (!ok)
                        ok = __hip_atomic_load(addr, __ATOMIC_RELAXED,
                                               __HIP_MEMORY_SCOPE_AGENT) >= 8u;
                    if (__ballot(ok) == ~0ull) break;
                    __builtin_amdgcn_s_sleep(1);
                }
            }
            // ACQUIRE fence: buffer_inv -> drop possibly stale L1/L2 h lines;
            // plain cached loads below refetch from L3.
            __builtin_amdgcn_fence(__ATOMIC_ACQUIRE, "agent");
        }
        __syncthreads();

        // ---- h burst: plain cached loads from blocked ring ----
        if (active && !havex) {
            const _Float16* hb; int ks;
            if (cell == 0)   { hb = h0r + (size_t)((p - 1) & 3) * 65536; ks = kq - 4; }
            else if (kq < 4) { hb = h0r + (size_t)((p - 1) & 3) * 65536; ks = kq; }
            else             { hb = h1r + (size_t)((p - 2) & 3) * 65536; ks = kq - 4; }
            // elem (b, k): ring[mb][k>>4][b][k&15]; lane k = ks*256+kt*32+q*8+j
            const _Float16* a = hb + (size_t)mb * 32768
                                + (size_t)(ks * 16 + (q >> 1)) * 512
                                + (size_t)n15 * 16 + (q & 1) * 8;
            #pragma unroll
            for (int mt = 0; mt < 2; ++mt)
                #pragma unroll
                for (int kt = 0; kt < 8; ++kt)
                    A[mt][kt] = *(const half8v*)(a + kt * 1024 + mt * 256);
        }

        // ---- MFMA; gate partials -> swizzled LDS via ds_write_b128 ----
        if (active) {
            #pragma unroll
            for (int mt = 0; mt < 2; ++mt) {
                f32x4 acc[4] = {{0.f,0.f,0.f,0.f}, {0.f,0.f,0.f,0.f},
                                {0.f,0.f,0.f,0.f}, {0.f,0.f,0.f,0.f}};
                #pragma unroll
                for (int kt = 0; kt < 8; ++kt)
                    #pragma unroll
                    for (int nt = 0; nt < 4; ++nt)
                        acc[nt] = __builtin_amdgcn_mfma_f32_16x16x32_f16(
                                      A[mt][kt], wreg[nt * 8 + kt], acc[nt], 0, 0, 0);
                const int row0 = mt * 16 + q * 4;
                #pragma unroll
                for (int nt = 0; nt < 4; ++nt) {
                    const int c = nt * 16 + n15;
                    // gates idx = (c*8 + kq)*32 + (m ^ ((c&7)<<2)); m=row0..+3
                    *(f32x4*)(gates + (c * 8 + kq) * 32
                                    + (row0 ^ ((c & 7) << 2))) = acc[nt];
                }
            }
        }
        __syncthreads();

        // ---- pointwise: reduce 8 partials/gate, fast tanh, direct h store ----
        if (active) {
            float gg[4];
            #pragma unroll
            for (int g = 0; g < 4; ++g) {
                const int c = g * 16 + pdn;
                const int key = (c & 7) << 2;
                float s = 0.f;
                #pragma unroll
                for (int k8 = 0; k8 < 8; ++k8)
                    s += gates[(c * 8 + k8) * 32 + (pm ^ key)];
                gg[g] = s;
            }
            float g0 = gg[0] + bi, g1 = gg[1] + bfg, g2 = gg[2] + bg, g3 = gg[3] + bo;
            float si = 1.f / (1.f + __expf(-g0));
            float sf = 1.f / (1.f + __expf(-g1));
            float so = 1.f / (1.f + __expf(-g3));
            float tg = 1.f - 2.f / (__expf(2.f * g2) + 1.f);
            float cn = sf * creg + si * tg;
            float tc = 1.f - 2.f / (__expf(2.f * cn) + 1.f);
            float hn = so * tc;
            creg = cn;
            if (p < TSTEPS) {
                union { _Float16 h; unsigned short u; } cv; cv.h = (_Float16)hn;
                _Float16* dst = (cell ? h1r + (size_t)((p - 1) & 3) * 65536
                                      : h0r + (size_t)(p & 3) * 65536)
                                + (size_t)mb * 32768 + (size_t)nb * 512;
                __hip_atomic_store((unsigned short*)dst + tid, cv.u,
                                   __ATOMIC_RELAXED, __HIP_MEMORY_SCOPE_AGENT);
            }
            if (cell && p == TSTEPS) out[(mb * 32 + pm) * 1024 + nb * 16 + pdn] = hn;
        }

        // ---- drain own stores, barrier, signal ----
        if (p < TSTEPS) {
            if (active) {
                asm volatile("s_waitcnt vmcnt(0)" ::: "memory");   // h at L3
                __syncthreads();
            }
            if (tid == 0)
                __hip_atomic_fetch_add(leafm + (p * 16 + (wb >> 3)) * 16, 1u,
                                       __ATOMIC_RELAXED, __HIP_MEMORY_SCOPE_AGENT);
        }
    }
}

extern "C" void kernel_launch(void* const* d_in, const int* in_sizes, int n_in,
                              void* d_out, int out_size, void* d_ws, size_t ws_size,
                              hipStream_t stream)
{
    const float* x   = (const float*)d_in[0];
    const float* Wx0 = (const float*)d_in[1];
    const float* Wh0 = (const float*)d_in[2];
    const float* b0  = (const float*)d_in[3];
    const float* Wx1 = (const float*)d_in[4];
    const float* Wh1 = (const float*)d_in[5];
    const float* b1  = (const float*)d_in[6];
    float* out = (float*)d_out;

    _Float16* xh   = (_Float16*)d_ws;
    _Float16* h0r  = xh + (size_t)16777216;
    _Float16* h1r  = h0r + 262144;
    unsigned* cnts = (unsigned*)(h1r + 262144);

    hipLaunchKernelGGL(prologue, dim3(2048), dim3(256), 0, stream, x, xh, h0r, cnts);

    size_t smem = 131072;
    (void)hipFuncSetAttribute((const void*)lstm_persistent,
                              hipFuncAttributeMaxDynamicSharedMemorySize, (int)smem);

    void* args[] = {(void*)&Wx0, (void*)&Wh0, (void*)&b0,
                    (void*)&Wx1, (void*)&Wh1, (void*)&b1,
                    (void*)&xh, (void*)&h0r, (void*)&h1r,
                    (void*)&cnts, (void*)&out};
    (void)hipLaunchCooperativeKernel((const void*)lstm_persistent, dim3(256), dim3(512),
                                     args, (unsigned)smem, stream);
}